// Round 15
// baseline (3221.849 us; speedup 1.0000x reference)
//
#include <hip/hip_runtime.h>
#include <math.h>

#define BS   256
#define NN   255
#define DIM  128
#define GAMMA 0.07
#define NUM_ITERS 1000

typedef float v2f __attribute__((ext_vector_type(2)));

__device__ __forceinline__ double wred_d(double v) {
  #pragma unroll
  for (int k = 1; k < 64; k <<= 1) v += __shfl_xor(v, k, 64);
  return v;
}
__device__ __forceinline__ int wred_i(int v) {
  #pragma unroll
  for (int k = 1; k < 64; k <<= 1) v += __shfl_xor(v, k, 64);
  return v;
}

// lane-uniform float readlane
__device__ __forceinline__ float RLF(float v, int lane) {
  return __int_as_float(__builtin_amdgcn_readlane(__float_as_int(v), lane));
}

// DPP wave64 sum -> total broadcast via readlane(63). VALU-only.
template <int CTRL, int RMASK>
__device__ __forceinline__ float dpp_add(float x) {
  int t = __builtin_amdgcn_update_dpp(0, __float_as_int(x), CTRL, RMASK, 0xf, true);
  return x + __int_as_float(t);
}
__device__ __forceinline__ float wred64_dpp(float x) {
  x = dpp_add<0x111, 0xf>(x);   // row_shr:1
  x = dpp_add<0x112, 0xf>(x);   // row_shr:2
  x = dpp_add<0x114, 0xf>(x);   // row_shr:4
  x = dpp_add<0x118, 0xf>(x);   // row_shr:8
  x = dpp_add<0x142, 0xa>(x);   // row_bcast:15
  x = dpp_add<0x143, 0xc>(x);   // row_bcast:31; lane63 = total
  return RLF(x, 63);
}

// fast reciprocal-sqrt: v_rsq_f32 + one Newton step (~0.5 ulp)
__device__ __forceinline__ float rsq_nr(float x) {
  float r;
  asm("v_rsq_f32 %0, %1" : "=v"(r) : "v"(x));
  r = r * (1.5f - 0.5f * x * r * r);
  return r;
}

// packed dual-fp32 FMA (VOP3P): acc.lo += k.lo*y.lo; acc.hi += k.hi*y.hi
__device__ __forceinline__ void pk_fma(v2f& acc, const v2f& k, const v2f& y) {
  asm("v_pk_fma_f32 %0, %1, %2, %0" : "+v"(acc) : "v"(k), "v"(y));
}

// ---------------- kernel 1: normalized features, stored transposed fp64 ----------------
__global__ void k_ftr(const float* __restrict__ z, double* __restrict__ ftrT) {
  int b = blockIdx.x;
  int d = threadIdx.x;
  double z0 = (double)z[b * 256 + d];
  double z1 = (double)z[b * 256 + 128 + d];
  double n = sqrt(z0 * z0 + z1 * z1);
  n = fmax(n, 1e-12);
  ftrT[d * 512 + b]       = z0 / n;
  ftrT[d * 512 + 256 + b] = z1 / n;
}

// ---------------- kernel 2: K = exp(-gamma * dist), fp64 math, fp32 store ----------------
__global__ void k_K(const double* __restrict__ ftrT, float* __restrict__ K,
                    double* __restrict__ pk_knt, double* __restrict__ pos_arr) {
  int i = blockIdx.x;
  int t = threadIdx.x;
  __shared__ double rowi[DIM];
  __shared__ double redd[4];
  if (t < DIM) rowi[t] = ftrT[t * 512 + i];
  __syncthreads();
  double xn = 0.0;
  #pragma unroll 8
  for (int d = 0; d < DIM; ++d) xn += rowi[d] * rowi[d];

  double knt_part = 0.0;
  #pragma unroll
  for (int h = 0; h < 2; ++h) {
    int j = t + h * 256;
    double dot = 0.0, sq = 0.0;
    #pragma unroll 8
    for (int d = 0; d < DIM; ++d) {
      double f = ftrT[d * 512 + j];
      dot += rowi[d] * f;
      sq  += f * f;
    }
    double dist = xn + sq - 2.0 * dot;
    double kv = exp(-GAMMA * dist);
    K[i * 512 + j] = (float)kv;
    if (h == 1) {
      if (j == 256 + i) pos_arr[i] = kv;
      else knt_part += kv;
    }
  }
  double w = wred_d(knt_part);
  if ((t & 63) == 0) redd[t >> 6] = w;
  __syncthreads();
  if (t == 0) pk_knt[i] = redd[0] + redd[1] + redd[2] + redd[3];
}

// ---------------- kernel 3: per-batch PGD — pk_fma + ds_add partials ----------------
// R14 skeleton (8 waves, 512 thr, 256-VGPR budget, wave rg owns rows
// [32rg,32rg+32), lane l owns cols 4l..4l+3) with two upgrades:
//  1. matvec via v_pk_fma_f32 on row-pairs: 64 pk_fma replaces 128 v_fmac.
//  2. partials accumulated IN PLACE via ds_add_f32 (atomicAdd on LDS) into a
//     double-buffered 256-float row; waves zero buf^1 during region1.
//     Region2's serial chain collapses: ONE b128 read (gA directly), no
//     8-load + 7-add tree (R14: ~450 cyc serial -> ~220).
// a==r exact cancel preserved: gr = readlane of the same loaded gA value.
__global__ __launch_bounds__(512, 2) void k_pgd(
    const float* __restrict__ K, const float* __restrict__ alpha_init,
    double* __restrict__ neg_arr, double* __restrict__ sa_arr,
    int* __restrict__ cnt1, int* __restrict__ cntp, int* __restrict__ cnt0) {
  int r = blockIdx.x;
  int tid = threadIdx.x;
  int l = tid & 63;
  int rg = tid >> 6;        // 0..7 = row band (32 rows each)

  __shared__ __align__(16) float ytil[BS];      // a-indexed, ytil[r]==0 always
  __shared__ __align__(16) float part[2][BS];   // double-buffered accum row, 2 KB
  __shared__ float S_lds[1];
  __shared__ float betat[1024];

  // beta table: betat[i] = i/(i+3) fp32 (read at index it+1)
  for (int i = tid; i < 1024; i += 512)
    betat[i] = (float)i / ((float)i + 3.0f);

  // stage K block as row-pair v2f: kq[16*k + j] = (K[32rg+2j][4l+k], K[32rg+2j+1][4l+k])
  v2f kq[64];
  #pragma unroll
  for (int j = 0; j < 16; ++j) {
    float4 r0 = *(const float4*)&K[(32 * rg + 2 * j + 0) * 512 + 4 * l];
    float4 r1 = *(const float4*)&K[(32 * rg + 2 * j + 1) * 512 + 4 * l];
    kq[j].x      = r0.x; kq[j].y      = r1.x;
    kq[16 + j].x = r0.y; kq[16 + j].y = r1.y;
    kq[32 + j].x = r0.z; kq[32 + j].y = r1.z;
    kq[48 + j].x = r0.w; kq[48 + j].y = r1.w;
  }
  #pragma unroll
  for (int j = 0; j < 64; ++j)
    asm volatile("" : "+v"(kq[j]));   // pin; block rematerialization

  // wave-0-only solver state: lane l holds a = 4l..4l+3 (dummy 0 at a==r)
  float al[4], ap[4], yv[4], kv[4], rm2[4];
  if (rg == 0) {
    #pragma unroll
    for (int k = 0; k < 4; ++k) {
      int a = 4 * l + k;
      if (a == r) {
        al[k] = 0.f; ap[k] = 0.f; yv[k] = 0.f; kv[k] = 0.f; rm2[k] = 0.f;
      } else {
        int c = a - (a > r ? 1 : 0);
        float v = alpha_init[r * NN + c];
        v = fminf(fmaxf(v, 0.f), 1.f);
        al[k] = v; ap[k] = v; yv[k] = v;
        kv[k] = 1.0f - K[r * 512 + a];
        rm2[k] = 2.0f;
      }
    }
    float4 y4 = {yv[0], yv[1], yv[2], yv[3]};
    *(float4*)&ytil[4 * l] = y4;     // a-indexed store (slot r holds 0)
  }
  // zero part[0] (used at it=0); part[1] zeroed during region1 of it=0
  {
    float4 z4 = {0.f, 0.f, 0.f, 0.f};
    if (l < 8) *(float4*)&part[0][32 * rg + 4 * l] = z4;
  }
  __syncthreads();                   // state + betat + part[0] visible

  int rq = r >> 2, rc = r & 3;       // location of column r in lane/comp grid

  for (int it = 0; it < NUM_ITERS; ++it) {
    int b = it & 1;
    // ---- phase A (all 8 waves): band matvec + zero buf^1; wave1 computes S ----
    if (rg == 1) {
      float4 yq = *(const float4*)&ytil[4 * l];
      float Sv = wred64_dpp((yq.x + yq.y) + (yq.z + yq.w));
      if (l == 0) S_lds[0] = Sv;
    }
    {
      float4 z4 = {0.f, 0.f, 0.f, 0.f};
      if (l < 8) *(float4*)&part[b ^ 1][32 * rg + 4 * l] = z4;  // safe: readers done pre-B2(it-1)
    }
    const float4* yb = (const float4*)&ytil[32 * rg];
    v2f a0 = {0.f, 0.f}, a1 = {0.f, 0.f}, a2 = {0.f, 0.f}, a3 = {0.f, 0.f};
    #pragma unroll
    for (int jj = 0; jj < 8; ++jj) {
      float4 yq = yb[jj];                      // wave-broadcast b128 (4 rows of y)
      v2f ylo = {yq.x, yq.y};
      v2f yhi = {yq.z, yq.w};
      pk_fma(a0, kq[2 * jj],     ylo); pk_fma(a0, kq[2 * jj + 1],      yhi);
      pk_fma(a1, kq[16 + 2 * jj], ylo); pk_fma(a1, kq[16 + 2 * jj + 1], yhi);
      pk_fma(a2, kq[32 + 2 * jj], ylo); pk_fma(a2, kq[32 + 2 * jj + 1], yhi);
      pk_fma(a3, kq[48 + 2 * jj], ylo); pk_fma(a3, kq[48 + 2 * jj + 1], yhi);
    }
    atomicAdd(&part[b][4 * l + 0], a0.x + a0.y);   // ds_add_f32, no return
    atomicAdd(&part[b][4 * l + 1], a1.x + a1.y);
    atomicAdd(&part[b][4 * l + 2], a2.x + a2.y);
    atomicAdd(&part[b][4 * l + 3], a3.x + a3.y);
    __syncthreads();                           // B1: all adds + S visible

    // ---- phase B: region2 on wave 0 only (single b128 read) ----
    if (rg == 0) {
      float4 gA = *(const float4*)&part[b][4 * l];
      float grv = (rc == 0) ? gA.x : (rc == 1) ? gA.y : (rc == 2) ? gA.z : gA.w;
      float gr = RLF(grv, rq);
      float Sv = S_lds[0];
      float beta = betat[it + 1];
      // a==r col: kv=rm2=yv=0 and gA==gr (same LDS value) -> g = 0 exactly
      float g[4];
      g[0] = (gA.x - gr) - rm2[0] + kv[0] * Sv + 0.1f * yv[0];
      g[1] = (gA.y - gr) - rm2[1] + kv[1] * Sv + 0.1f * yv[1];
      g[2] = (gA.z - gr) - rm2[2] + kv[2] * Sv + 0.1f * yv[2];
      g[3] = (gA.w - gr) - rm2[3] + kv[3] * Sv + 0.1f * yv[3];
      float n2 = wred64_dpp((g[0] * g[0] + g[1] * g[1]) + (g[2] * g[2] + g[3] * g[3]));
      float sinv = 0.001f * rsq_nr(n2);
      #pragma unroll
      for (int k = 0; k < 4; ++k) {
        float na = fminf(fmaxf(fmaf(-sinv, g[k], yv[k]), 0.f), 1.f);
        ap[k] = al[k];
        al[k] = na;
        yv[k] = fmaf(beta, na - ap[k], na);
      }
      float4 y4 = {yv[0], yv[1], yv[2], yv[3]};
      *(float4*)&ytil[4 * l] = y4;             // one b128, conflict-free
    }
    __syncthreads();                           // B2: ytil ready
  }

  // epilogue: wave 0 holds the state — single-wave fp64 reductions
  if (rg == 0) {
    double nl = 0.0, sa = 0.0;
    int c1 = 0, cp = 0, cz = 0;
    #pragma unroll
    for (int k = 0; k < 4; ++k) {
      int a = 4 * l + k;
      if (a != r) {
        float kx = K[a * 512 + 256 + r];     // KnT[r, c(a)]
        nl += (double)al[k] * (double)kx;
        sa += (double)al[k];
        c1 += (al[k] == 1.0f);
        cp += (al[k] > 0.0f);
        cz += (al[k] == 0.0f);
      }
    }
    nl = wred_d(nl); sa = wred_d(sa);
    c1 = wred_i(c1); cp = wred_i(cp); cz = wred_i(cz);
    if (l == 0) {
      neg_arr[r] = nl;
      sa_arr[r]  = sa;
      cnt1[r] = c1; cntp[r] = cp; cnt0[r] = cz;
    }
  }
}

// ---------------- kernel 4: final reduction to the 6 scalar outputs ----------------
__global__ void k_fin(const double* __restrict__ pk_knt, const double* __restrict__ pos_arr,
                      const double* __restrict__ neg_arr, const double* __restrict__ sa_arr,
                      const int* __restrict__ cnt1, const int* __restrict__ cntp,
                      const int* __restrict__ cnt0, float* __restrict__ out) {
  int t = threadIdx.x;  // 256
  __shared__ double rd[16];
  __shared__ int ri[12];
  double knt = pk_knt[t];
  double pos = pos_arr[t];
  double neg = neg_arr[t];
  double pl  = sa_arr[t] * pos_arr[t];
  int a1 = cnt1[t], ap = cntp[t], a0 = cnt0[t];
  knt = wred_d(knt); pos = wred_d(pos); neg = wred_d(neg); pl = wred_d(pl);
  a1 = wred_i(a1); ap = wred_i(ap); a0 = wred_i(a0);
  int w = t >> 6;
  if ((t & 63) == 0) {
    rd[w] = knt; rd[4 + w] = pos; rd[8 + w] = neg; rd[12 + w] = pl;
    ri[w] = a1; ri[4 + w] = ap; ri[8 + w] = a0;
  }
  __syncthreads();
  if (t == 0) {
    double kntS = rd[0] + rd[1] + rd[2] + rd[3];
    double posS = rd[4] + rd[5] + rd[6] + rd[7];
    double negS = rd[8] + rd[9] + rd[10] + rd[11];
    double plS  = rd[12] + rd[13] + rd[14] + rd[15];
    int c1t = ri[0] + ri[1] + ri[2] + ri[3];
    int cpt = ri[4] + ri[5] + ri[6] + ri[7];
    int c0t = ri[8] + ri[9] + ri[10] + ri[11];
    out[0] = (float)(negS / 256.0 - plS / 256.0);
    out[1] = (float)(posS / 256.0);
    out[2] = (float)(kntS / (256.0 * 255.0));
    out[3] = (float)c1t / ((float)cpt + 1e-10f);
    out[4] = (float)c0t / 65280.0f;
    out[5] = 0.0f;
  }
}

extern "C" void kernel_launch(void* const* d_in, const int* in_sizes, int n_in,
                              void* d_out, int out_size, void* d_ws, size_t ws_size,
                              hipStream_t stream) {
  const float* z     = (const float*)d_in[0];
  const float* ainit = (const float*)d_in[1];
  char* ws = (char*)d_ws;
  double* ftrT   = (double*)ws;                       // 512 KB
  float*  K      = (float*)(ws + 524288);             // 512 KB
  double* pk_knt = (double*)(ws + 1048576);
  double* pos_a  = (double*)(ws + 1048576 + 2048);
  double* neg_a  = (double*)(ws + 1048576 + 4096);
  double* sa_a   = (double*)(ws + 1048576 + 6144);
  int* cnt1 = (int*)(ws + 1048576 + 8192);
  int* cntp = (int*)(ws + 1048576 + 8192 + 1024);
  int* cnt0 = (int*)(ws + 1048576 + 8192 + 2048);
  float* out = (float*)d_out;

  k_ftr<<<256, 128, 0, stream>>>(z, ftrT);
  k_K  <<<256, 256, 0, stream>>>(ftrT, K, pk_knt, pos_a);
  k_pgd<<<256, 512, 0, stream>>>(K, ainit, neg_a, sa_a, cnt1, cntp, cnt0);
  k_fin<<<1, 256, 0, stream>>>(pk_knt, pos_a, neg_a, sa_a, cnt1, cntp, cnt0, out);
}

// Round 16
// 814.774 us; speedup vs baseline: 3.9543x; 3.9543x over previous
//
#include <hip/hip_runtime.h>
#include <math.h>

#define BS   256
#define NN   255
#define DIM  128
#define GAMMA 0.07
#define NUM_ITERS 1000

typedef float v2f __attribute__((ext_vector_type(2)));

__device__ __forceinline__ double wred_d(double v) {
  #pragma unroll
  for (int k = 1; k < 64; k <<= 1) v += __shfl_xor(v, k, 64);
  return v;
}
__device__ __forceinline__ int wred_i(int v) {
  #pragma unroll
  for (int k = 1; k < 64; k <<= 1) v += __shfl_xor(v, k, 64);
  return v;
}

// lane-uniform float readlane
__device__ __forceinline__ float RLF(float v, int lane) {
  return __int_as_float(__builtin_amdgcn_readlane(__float_as_int(v), lane));
}

// DPP wave64 sum -> total broadcast via readlane(63). VALU-only.
template <int CTRL, int RMASK>
__device__ __forceinline__ float dpp_add(float x) {
  int t = __builtin_amdgcn_update_dpp(0, __float_as_int(x), CTRL, RMASK, 0xf, true);
  return x + __int_as_float(t);
}
__device__ __forceinline__ float wred64_dpp(float x) {
  x = dpp_add<0x111, 0xf>(x);   // row_shr:1
  x = dpp_add<0x112, 0xf>(x);   // row_shr:2
  x = dpp_add<0x114, 0xf>(x);   // row_shr:4
  x = dpp_add<0x118, 0xf>(x);   // row_shr:8
  x = dpp_add<0x142, 0xa>(x);   // row_bcast:15
  x = dpp_add<0x143, 0xc>(x);   // row_bcast:31; lane63 = total
  return RLF(x, 63);
}

// fast reciprocal-sqrt: v_rsq_f32 + one Newton step (~0.5 ulp)
__device__ __forceinline__ float rsq_nr(float x) {
  float r;
  asm("v_rsq_f32 %0, %1" : "=v"(r) : "v"(x));
  r = r * (1.5f - 0.5f * x * r * r);
  return r;
}

// packed dual-fp32 FMA (VOP3P): acc.lo += k.lo*y.lo; acc.hi += k.hi*y.hi
__device__ __forceinline__ void pk_fma(v2f& acc, const v2f& k, const v2f& y) {
  asm("v_pk_fma_f32 %0, %1, %2, %0" : "+v"(acc) : "v"(k), "v"(y));
}

__device__ __forceinline__ float4 add4(float4 a, float4 b) {
  float4 c; c.x = a.x + b.x; c.y = a.y + b.y; c.z = a.z + b.z; c.w = a.w + b.w;
  return c;
}

// ---------------- kernel 1: normalized features, stored transposed fp64 ----------------
__global__ void k_ftr(const float* __restrict__ z, double* __restrict__ ftrT) {
  int b = blockIdx.x;
  int d = threadIdx.x;
  double z0 = (double)z[b * 256 + d];
  double z1 = (double)z[b * 256 + 128 + d];
  double n = sqrt(z0 * z0 + z1 * z1);
  n = fmax(n, 1e-12);
  ftrT[d * 512 + b]       = z0 / n;
  ftrT[d * 512 + 256 + b] = z1 / n;
}

// ---------------- kernel 2: K = exp(-gamma * dist), fp64 math, fp32 store ----------------
__global__ void k_K(const double* __restrict__ ftrT, float* __restrict__ K,
                    double* __restrict__ pk_knt, double* __restrict__ pos_arr) {
  int i = blockIdx.x;
  int t = threadIdx.x;
  __shared__ double rowi[DIM];
  __shared__ double redd[4];
  if (t < DIM) rowi[t] = ftrT[t * 512 + i];
  __syncthreads();
  double xn = 0.0;
  #pragma unroll 8
  for (int d = 0; d < DIM; ++d) xn += rowi[d] * rowi[d];

  double knt_part = 0.0;
  #pragma unroll
  for (int h = 0; h < 2; ++h) {
    int j = t + h * 256;
    double dot = 0.0, sq = 0.0;
    #pragma unroll 8
    for (int d = 0; d < DIM; ++d) {
      double f = ftrT[d * 512 + j];
      dot += rowi[d] * f;
      sq  += f * f;
    }
    double dist = xn + sq - 2.0 * dot;
    double kv = exp(-GAMMA * dist);
    K[i * 512 + j] = (float)kv;
    if (h == 1) {
      if (j == 256 + i) pos_arr[i] = kv;
      else knt_part += kv;
    }
  }
  double w = wred_d(knt_part);
  if ((t & 63) == 0) redd[t >> 6] = w;
  __syncthreads();
  if (t == 0) pk_knt[i] = redd[0] + redd[1] + redd[2] + redd[3];
}

// ---------------- kernel 3: per-batch PGD — R14 skeleton + pk_fma matvec ----------------
// 8 waves, 512 thr, 256-VGPR budget. Wave rg owns rows [32rg,32rg+32); lane l
// owns cols 4l..4l+3. kq staged as 64 v2f row-pairs (128 regs); matvec =
// 8 bcast b128 y-reads + 64 v_pk_fma_f32 + 1 b128 part write per thread.
// Region2 on wave0: 8 b128 part loads + tree (R14-exact arithmetic).
// R15 lesson: NO LDS atomics on the iteration path (3.9x regression).
__global__ __launch_bounds__(512, 2) void k_pgd(
    const float* __restrict__ K, const float* __restrict__ alpha_init,
    double* __restrict__ neg_arr, double* __restrict__ sa_arr,
    int* __restrict__ cnt1, int* __restrict__ cntp, int* __restrict__ cnt0) {
  int r = blockIdx.x;
  int tid = threadIdx.x;
  int l = tid & 63;
  int rg = tid >> 6;        // 0..7 = row band (32 rows each)

  __shared__ __align__(16) float ytil[BS];      // a-indexed, ytil[r]==0 always
  __shared__ __align__(16) float part[8][BS];   // [band][a-col], 8 KB
  __shared__ float S_lds[1];
  __shared__ float betat[1024];

  // beta table: betat[i] = i/(i+3) fp32 (read at index it+1)
  for (int i = tid; i < 1024; i += 512)
    betat[i] = (float)i / ((float)i + 3.0f);

  // stage K block as row-pair v2f: kq[16*k + j] = (K[32rg+2j][4l+k], K[32rg+2j+1][4l+k])
  v2f kq[64];
  #pragma unroll
  for (int j = 0; j < 16; ++j) {
    float4 r0 = *(const float4*)&K[(32 * rg + 2 * j + 0) * 512 + 4 * l];
    float4 r1 = *(const float4*)&K[(32 * rg + 2 * j + 1) * 512 + 4 * l];
    kq[j].x      = r0.x; kq[j].y      = r1.x;
    kq[16 + j].x = r0.y; kq[16 + j].y = r1.y;
    kq[32 + j].x = r0.z; kq[32 + j].y = r1.z;
    kq[48 + j].x = r0.w; kq[48 + j].y = r1.w;
  }
  #pragma unroll
  for (int j = 0; j < 64; ++j)
    asm volatile("" : "+v"(kq[j]));   // pin; block rematerialization

  // wave-0-only solver state: lane l holds a = 4l..4l+3 (dummy 0 at a==r)
  float al[4], ap[4], yv[4], kv[4], rm2[4];
  if (rg == 0) {
    #pragma unroll
    for (int k = 0; k < 4; ++k) {
      int a = 4 * l + k;
      if (a == r) {
        al[k] = 0.f; ap[k] = 0.f; yv[k] = 0.f; kv[k] = 0.f; rm2[k] = 0.f;
      } else {
        int c = a - (a > r ? 1 : 0);
        float v = alpha_init[r * NN + c];
        v = fminf(fmaxf(v, 0.f), 1.f);
        al[k] = v; ap[k] = v; yv[k] = v;
        kv[k] = 1.0f - K[r * 512 + a];
        rm2[k] = 2.0f;
      }
    }
    float4 y4 = {yv[0], yv[1], yv[2], yv[3]};
    *(float4*)&ytil[4 * l] = y4;     // a-indexed store (slot r holds 0)
  }
  __syncthreads();                   // state + betat visible

  int rq = r >> 2, rc = r & 3;       // location of column r in lane/comp grid

  for (int it = 0; it < NUM_ITERS; ++it) {
    // ---- phase A (all 8 waves): band matvec; wave1 computes S off-path ----
    if (rg == 1) {
      float4 yq = *(const float4*)&ytil[4 * l];
      float Sv = wred64_dpp((yq.x + yq.y) + (yq.z + yq.w));
      if (l == 0) S_lds[0] = Sv;
    }
    const float4* yb = (const float4*)&ytil[32 * rg];
    v2f a0 = {0.f, 0.f}, a1 = {0.f, 0.f}, a2 = {0.f, 0.f}, a3 = {0.f, 0.f};
    #pragma unroll
    for (int jj = 0; jj < 8; ++jj) {
      float4 yq = yb[jj];                      // wave-broadcast b128 (4 rows of y)
      v2f ylo = {yq.x, yq.y};
      v2f yhi = {yq.z, yq.w};
      pk_fma(a0, kq[2 * jj],      ylo); pk_fma(a0, kq[2 * jj + 1],      yhi);
      pk_fma(a1, kq[16 + 2 * jj], ylo); pk_fma(a1, kq[16 + 2 * jj + 1], yhi);
      pk_fma(a2, kq[32 + 2 * jj], ylo); pk_fma(a2, kq[32 + 2 * jj + 1], yhi);
      pk_fma(a3, kq[48 + 2 * jj], ylo); pk_fma(a3, kq[48 + 2 * jj + 1], yhi);
    }
    float4 accw = {a0.x + a0.y, a1.x + a1.y, a2.x + a2.y, a3.x + a3.y};
    *(float4*)&part[rg][4 * l] = accw;         // conflict-free b128 write
    __syncthreads();                           // B1: partials + S visible

    // ---- phase B: region2 on wave 0 only ----
    if (rg == 0) {
      float4 q0 = *(const float4*)&part[0][4 * l];
      float4 q1 = *(const float4*)&part[1][4 * l];
      float4 q2 = *(const float4*)&part[2][4 * l];
      float4 q3 = *(const float4*)&part[3][4 * l];
      float4 q4 = *(const float4*)&part[4][4 * l];
      float4 q5 = *(const float4*)&part[5][4 * l];
      float4 q6 = *(const float4*)&part[6][4 * l];
      float4 q7 = *(const float4*)&part[7][4 * l];
      float4 gA = add4(add4(add4(q0, q1), add4(q2, q3)),
                       add4(add4(q4, q5), add4(q6, q7)));
      // gr = gA at column r (uniform rc select + readlane)
      float grv = (rc == 0) ? gA.x : (rc == 1) ? gA.y : (rc == 2) ? gA.z : gA.w;
      float gr = RLF(grv, rq);
      float Sv = S_lds[0];
      float beta = betat[it + 1];
      // a==r col: kv=rm2=yv=0 and gA==gr -> g = 0 exactly
      float g[4];
      g[0] = (gA.x - gr) - rm2[0] + kv[0] * Sv + 0.1f * yv[0];
      g[1] = (gA.y - gr) - rm2[1] + kv[1] * Sv + 0.1f * yv[1];
      g[2] = (gA.z - gr) - rm2[2] + kv[2] * Sv + 0.1f * yv[2];
      g[3] = (gA.w - gr) - rm2[3] + kv[3] * Sv + 0.1f * yv[3];
      float n2 = wred64_dpp((g[0] * g[0] + g[1] * g[1]) + (g[2] * g[2] + g[3] * g[3]));
      float sinv = 0.001f * rsq_nr(n2);
      #pragma unroll
      for (int k = 0; k < 4; ++k) {
        float na = fminf(fmaxf(fmaf(-sinv, g[k], yv[k]), 0.f), 1.f);
        ap[k] = al[k];
        al[k] = na;
        yv[k] = fmaf(beta, na - ap[k], na);
      }
      float4 y4 = {yv[0], yv[1], yv[2], yv[3]};
      *(float4*)&ytil[4 * l] = y4;             // one b128, conflict-free
    }
    __syncthreads();                           // B2: ytil ready
  }

  // epilogue: wave 0 holds the state — single-wave fp64 reductions
  if (rg == 0) {
    double nl = 0.0, sa = 0.0;
    int c1 = 0, cp = 0, cz = 0;
    #pragma unroll
    for (int k = 0; k < 4; ++k) {
      int a = 4 * l + k;
      if (a != r) {
        float kx = K[a * 512 + 256 + r];     // KnT[r, c(a)]
        nl += (double)al[k] * (double)kx;
        sa += (double)al[k];
        c1 += (al[k] == 1.0f);
        cp += (al[k] > 0.0f);
        cz += (al[k] == 0.0f);
      }
    }
    nl = wred_d(nl); sa = wred_d(sa);
    c1 = wred_i(c1); cp = wred_i(cp); cz = wred_i(cz);
    if (l == 0) {
      neg_arr[r] = nl;
      sa_arr[r]  = sa;
      cnt1[r] = c1; cntp[r] = cp; cnt0[r] = cz;
    }
  }
}

// ---------------- kernel 4: final reduction to the 6 scalar outputs ----------------
__global__ void k_fin(const double* __restrict__ pk_knt, const double* __restrict__ pos_arr,
                      const double* __restrict__ neg_arr, const double* __restrict__ sa_arr,
                      const int* __restrict__ cnt1, const int* __restrict__ cntp,
                      const int* __restrict__ cnt0, float* __restrict__ out) {
  int t = threadIdx.x;  // 256
  __shared__ double rd[16];
  __shared__ int ri[12];
  double knt = pk_knt[t];
  double pos = pos_arr[t];
  double neg = neg_arr[t];
  double pl  = sa_arr[t] * pos_arr[t];
  int a1 = cnt1[t], ap = cntp[t], a0 = cnt0[t];
  knt = wred_d(knt); pos = wred_d(pos); neg = wred_d(neg); pl = wred_d(pl);
  a1 = wred_i(a1); ap = wred_i(ap); a0 = wred_i(a0);
  int w = t >> 6;
  if ((t & 63) == 0) {
    rd[w] = knt; rd[4 + w] = pos; rd[8 + w] = neg; rd[12 + w] = pl;
    ri[w] = a1; ri[4 + w] = ap; ri[8 + w] = a0;
  }
  __syncthreads();
  if (t == 0) {
    double kntS = rd[0] + rd[1] + rd[2] + rd[3];
    double posS = rd[4] + rd[5] + rd[6] + rd[7];
    double negS = rd[8] + rd[9] + rd[10] + rd[11];
    double plS  = rd[12] + rd[13] + rd[14] + rd[15];
    int c1t = ri[0] + ri[1] + ri[2] + ri[3];
    int cpt = ri[4] + ri[5] + ri[6] + ri[7];
    int c0t = ri[8] + ri[9] + ri[10] + ri[11];
    out[0] = (float)(negS / 256.0 - plS / 256.0);
    out[1] = (float)(posS / 256.0);
    out[2] = (float)(kntS / (256.0 * 255.0));
    out[3] = (float)c1t / ((float)cpt + 1e-10f);
    out[4] = (float)c0t / 65280.0f;
    out[5] = 0.0f;
  }
}

extern "C" void kernel_launch(void* const* d_in, const int* in_sizes, int n_in,
                              void* d_out, int out_size, void* d_ws, size_t ws_size,
                              hipStream_t stream) {
  const float* z     = (const float*)d_in[0];
  const float* ainit = (const float*)d_in[1];
  char* ws = (char*)d_ws;
  double* ftrT   = (double*)ws;                       // 512 KB
  float*  K      = (float*)(ws + 524288);             // 512 KB
  double* pk_knt = (double*)(ws + 1048576);
  double* pos_a  = (double*)(ws + 1048576 + 2048);
  double* neg_a  = (double*)(ws + 1048576 + 4096);
  double* sa_a   = (double*)(ws + 1048576 + 6144);
  int* cnt1 = (int*)(ws + 1048576 + 8192);
  int* cntp = (int*)(ws + 1048576 + 8192 + 1024);
  int* cnt0 = (int*)(ws + 1048576 + 8192 + 2048);
  float* out = (float*)d_out;

  k_ftr<<<256, 128, 0, stream>>>(z, ftrT);
  k_K  <<<256, 256, 0, stream>>>(ftrT, K, pk_knt, pos_a);
  k_pgd<<<256, 512, 0, stream>>>(K, ainit, neg_a, sa_a, cnt1, cntp, cnt0);
  k_fin<<<1, 256, 0, stream>>>(pk_knt, pos_a, neg_a, sa_a, cnt1, cntp, cnt0, out);
}